// Round 8
// baseline (368.687 us; speedup 1.0000x reference)
//
#include <hip/hip_runtime.h>
#include <hip/hip_bf16.h>

// Problem constants
constexpr int BATCH = 8192;   // M
constexpr int THEADS = 137;   // number of predict heads
constexpr int DFEA = 384;     // reduction dim of GEMM1
constexpr int KHID = 128;     // per-head hidden width
constexpr float EPS_BN = 1e-5f;
constexpr float SLOPE = 0.01f;

constexpr size_t N_F  = (size_t)BATCH * DFEA;          // 3,145,728
constexpr size_t N_W1 = (size_t)THEADS * KHID * DFEA;  // 6,733,824
constexpr size_t WS_NEED = (N_F + N_W1) * sizeof(__hip_bfloat16);
constexpr int C_F8 = (int)(N_F / 8);                   // 393,216
constexpr int C_T8 = (int)((N_F + N_W1) / 8);          // 1,234,944

typedef __attribute__((ext_vector_type(8))) short bf16x8;   // 8 bf16 = 4 VGPRs
typedef __attribute__((ext_vector_type(4))) float f32x4;

__device__ __forceinline__ short cvt_bf16(float x) {
    __hip_bfloat16 b = __float2bfloat16(x);
    return *(short*)&b;
}

__device__ __forceinline__ bf16x8 load8_cvt(const float* __restrict__ g) {
    f32x4 lo = *(const f32x4*)g;
    f32x4 hi = *(const f32x4*)(g + 4);
    bf16x8 r;
    r[0] = cvt_bf16(lo[0]); r[1] = cvt_bf16(lo[1]);
    r[2] = cvt_bf16(lo[2]); r[3] = cvt_bf16(lo[3]);
    r[4] = cvt_bf16(hi[0]); r[5] = cvt_bf16(hi[1]);
    r[6] = cvt_bf16(hi[2]); r[7] = cvt_bf16(hi[3]);
    return r;
}

__device__ __forceinline__ void gload16(const void* g, void* s) {
    // async global->LDS, 16B/lane; HW dest = readfirstlane(base) + lane*16
    __builtin_amdgcn_global_load_lds((const __attribute__((address_space(1))) void*)g,
                                     (__attribute__((address_space(3))) void*)s,
                                     16, 0, 0);
}

// ---------------- pre-pass: fp32 -> bf16 bulk convert (f then W1, one launch) ----
__global__ __launch_bounds__(256) void cvt_pass(const float* __restrict__ f,
                                                const float* __restrict__ W1,
                                                __hip_bfloat16* __restrict__ ws) {
    int i = blockIdx.x * 256 + threadIdx.x;
    if (i < C_F8)
        *(bf16x8*)(ws + (size_t)i * 8) = load8_cvt(f + (size_t)i * 8);
    else if (i < C_T8)
        *(bf16x8*)(ws + (size_t)i * 8) = load8_cvt(W1 + ((size_t)i - C_F8) * 8);
}

// ------------- main kernel: B-resident, barrier-free K-loop ----------------------
// Block = (head t, 256 rows of f). The head's ENTIRE W1 slice (128x384 bf16 =
// 96 KB) is staged into LDS once (one barrier). The K-loop then has ZERO
// barriers: B is read-only in LDS, A-fragments are plain global->register
// loads (identical 16x64B-segment pattern as staging reads), so the compiler
// emits fine-grained vmcnt/lgkm waits and keeps loads in flight across the
// whole unrolled loop — no vmcnt(0) barrier drains (the round-5/6/7 limiter).
// 8 waves (512 thr): wave (wm 0..3, wn 0..1) computes 64 rows x 64 cols,
// acc[4][4] = 64 AGPR. B-LDS chunk-XOR swizzle: chunk c of row r stored at
// (c&~7)|((c^r)&7) -> frag reads conflict-free (lanes 0-7 span 32 banks).
__global__ __launch_bounds__(512, 2) void fused_heads_bf16(
    const __hip_bfloat16* __restrict__ fb,     // [8192, 384] bf16
    const __hip_bfloat16* __restrict__ W1b,    // [137*128, 384] bf16
    const float* __restrict__ b1,
    const float* __restrict__ gmm,
    const float* __restrict__ bta,
    const float* __restrict__ rmean,
    const float* __restrict__ rvar,
    const float* __restrict__ W2,
    const float* __restrict__ b2,
    float* __restrict__ out)                   // [8192, 137]
{
    __shared__ __attribute__((aligned(16))) __hip_bfloat16 Bs[KHID * DFEA]; // 96 KB
    __shared__ float red[2][256];

    const int tid  = threadIdx.x;
    const int lane = tid & 63;
    const int wave = tid >> 6;
    const int wm   = wave >> 1;      // M-slice 0..3 (64 rows each)
    const int wn   = wave & 1;       // N-half 0..1 (64 cols each)
    const int t  = blockIdx.x;
    const int m0 = blockIdx.y * 256;
    const int n0 = t * KHID;

    const int row16 = lane & 15;
    const int quad  = lane >> 4;

    // ---- B init: 128 rows x 48 chunks(16B) = 6144 chunks; 12 per thread ----
    #pragma unroll
    for (int j = 0; j < 12; ++j) {
        const int li = tid + j * 512;
        const int r  = li / 48, cp = li % 48;            // dest row / dest chunk
        const int c  = (cp & ~7) | ((cp ^ r) & 7);       // source chunk (XOR self-inverse)
        gload16(W1b + (size_t)(n0 + r) * DFEA + c * 8, &Bs[(size_t)li * 8]);
    }

    // A-frag base for this lane: row m0+wm*64+row16 (+ai*16), k-offset quad*8
    const __hip_bfloat16* aBase =
        fb + (size_t)(m0 + wm * 64 + row16) * DFEA + quad * 8;

    f32x4 acc[4][4];
    #pragma unroll
    for (int i = 0; i < 4; ++i)
        #pragma unroll
        for (int j = 0; j < 4; ++j)
            acc[i][j] = (f32x4){0.f, 0.f, 0.f, 0.f};

    bf16x8 af[4], an[4];
    #pragma unroll
    for (int ai = 0; ai < 4; ++ai)
        af[ai] = *(const bf16x8*)(aBase + (size_t)ai * 16 * DFEA);   // kstep 0

    __syncthreads();   // B tile valid (also covers the af loads above)

    #pragma unroll
    for (int kt = 0; kt < DFEA / 32; ++kt) {
        if (kt + 1 < DFEA / 32) {
            #pragma unroll
            for (int ai = 0; ai < 4; ++ai)
                an[ai] = *(const bf16x8*)(aBase + (size_t)ai * 16 * DFEA + (kt + 1) * 32);
        }

        bf16x8 bfr[4];
        const int c = kt * 4 + quad;                     // k-chunk of this lane
        #pragma unroll
        for (int bi = 0; bi < 4; ++bi) {
            const int nl = wn * 64 + bi * 16 + row16;    // local B row (col of head)
            const int cp = (c & ~7) | ((c ^ nl) & 7);    // swizzled chunk
            bfr[bi] = *(const bf16x8*)&Bs[(size_t)nl * DFEA + cp * 8];
        }

        #pragma unroll
        for (int ai = 0; ai < 4; ++ai)
            #pragma unroll
            for (int bi = 0; bi < 4; ++bi)
                acc[ai][bi] = __builtin_amdgcn_mfma_f32_16x16x32_bf16(
                    af[ai], bfr[bi], acc[ai][bi], 0, 0, 0);

        #pragma unroll
        for (int ai = 0; ai < 4; ++ai)
            af[ai] = an[ai];
    }

    // ---- fused epilogue: BN (eval) + LeakyReLU + dot with W2 ----
    float s[4], cc[4], w2v[4];
    #pragma unroll
    for (int bi = 0; bi < 4; ++bi) {
        const int n = n0 + wn * 64 + bi * 16 + row16;    // this lane's column
        const float sv = gmm[n] * rsqrtf(rvar[n] + EPS_BN);
        s[bi]   = sv;
        cc[bi]  = bta[n] + (b1[n] - rmean[n]) * sv;
        w2v[bi] = W2[n];
    }

    float p[4][4];
    #pragma unroll
    for (int ai = 0; ai < 4; ++ai)
        #pragma unroll
        for (int r = 0; r < 4; ++r) {
            float a = 0.f;
            #pragma unroll
            for (int bi = 0; bi < 4; ++bi) {
                float y = acc[ai][bi][r] * s[bi] + cc[bi];
                y = (y >= 0.f) ? y : SLOPE * y;          // LeakyReLU
                a += y * w2v[bi];
            }
            p[ai][r] = a;
        }

    // reduce across the 16 column-lanes (C/D: col = lane&15)
    #pragma unroll
    for (int mask = 1; mask <= 8; mask <<= 1)
        #pragma unroll
        for (int ai = 0; ai < 4; ++ai)
            #pragma unroll
            for (int r = 0; r < 4; ++r)
                p[ai][r] += __shfl_xor(p[ai][r], mask);

    __syncthreads();   // Bs reads all done; red[] may alias timing-wise — fence
    if (row16 == 0) {
        #pragma unroll
        for (int ai = 0; ai < 4; ++ai)
            #pragma unroll
            for (int r = 0; r < 4; ++r)
                red[wn][wm * 64 + ai * 16 + quad * 4 + r] = p[ai][r];
    }
    __syncthreads();

    if (tid < 256) {
        const float v = red[0][tid] + red[1][tid] + b2[t];
        out[(size_t)(m0 + tid) * THEADS + t] = v;
    }
}

// ---------------- fallback: direct fp32 path (round-3 kernel, 128-tile) ------------
__global__ __launch_bounds__(256) void fused_heads_f32(
    const float* __restrict__ f, const float* __restrict__ W1,
    const float* __restrict__ b1, const float* __restrict__ gmm,
    const float* __restrict__ bta, const float* __restrict__ rmean,
    const float* __restrict__ rvar, const float* __restrict__ W2,
    const float* __restrict__ b2, float* __restrict__ out)
{
    __shared__ __attribute__((aligned(16))) __hip_bfloat16 As[128 * 32];
    __shared__ __attribute__((aligned(16))) __hip_bfloat16 Bs[128 * 32];
    __shared__ float red[2][128];

    const int tid  = threadIdx.x;
    const int lane = tid & 63;
    const int wave = tid >> 6;
    const int wm = wave >> 1, wn = wave & 1;
    const int m0 = blockIdx.x * 128;
    const int t  = blockIdx.y;
    const int n0 = t * KHID;

    const int li0 = tid, li1 = tid + 256;
    const int r0 = li0 >> 2, c0 = (li0 & 3) * 8;
    const int r1 = li1 >> 2, c1 = (li1 & 3) * 8;
    const float* gA0 = f  + (size_t)(m0 + r0) * DFEA + c0;
    const float* gA1 = f  + (size_t)(m0 + r1) * DFEA + c1;
    const float* gB0 = W1 + (size_t)(n0 + r0) * DFEA + c0;
    const float* gB1 = W1 + (size_t)(n0 + r1) * DFEA + c1;

    const int row16 = lane & 15, quad = lane >> 4;

    f32x4 acc[4][4];
    #pragma unroll
    for (int i = 0; i < 4; ++i)
        #pragma unroll
        for (int j = 0; j < 4; ++j)
            acc[i][j] = (f32x4){0.f, 0.f, 0.f, 0.f};

    #pragma unroll 1
    for (int kt = 0; kt < DFEA / 32; ++kt) {
        const int k0 = kt * 32;
        bf16x8 va0 = load8_cvt(gA0 + k0);
        bf16x8 va1 = load8_cvt(gA1 + k0);
        bf16x8 vb0 = load8_cvt(gB0 + k0);
        bf16x8 vb1 = load8_cvt(gB1 + k0);
        __syncthreads();
        *(bf16x8*)&As[li0 * 8] = va0;
        *(bf16x8*)&As[li1 * 8] = va1;
        *(bf16x8*)&Bs[li0 * 8] = vb0;
        *(bf16x8*)&Bs[li1 * 8] = vb1;
        __syncthreads();

        bf16x8 af[4], bfr[4];
        #pragma unroll
        for (int i = 0; i < 4; ++i)
            af[i] = *(const bf16x8*)&As[(wm * 64 + i * 16 + row16) * 32 + quad * 8];
        #pragma unroll
        for (int i = 0; i < 4; ++i)
            bfr[i] = *(const bf16x8*)&Bs[(wn * 64 + i * 16 + row16) * 32 + quad * 8];
        #pragma unroll
        for (int ai = 0; ai < 4; ++ai)
            #pragma unroll
            for (int bi = 0; bi < 4; ++bi)
                acc[ai][bi] = __builtin_amdgcn_mfma_f32_16x16x32_bf16(
                    af[ai], bfr[bi], acc[ai][bi], 0, 0, 0);
    }

    float s[4], cc[4], w2v[4];
    #pragma unroll
    for (int bi = 0; bi < 4; ++bi) {
        const int n = n0 + wn * 64 + bi * 16 + row16;
        const float sv = gmm[n] * rsqrtf(rvar[n] + EPS_BN);
        s[bi] = sv;
        cc[bi] = bta[n] + (b1[n] - rmean[n]) * sv;
        w2v[bi] = W2[n];
    }
    float p[4][4];
    #pragma unroll
    for (int ai = 0; ai < 4; ++ai)
        #pragma unroll
        for (int r = 0; r < 4; ++r) {
            float a = 0.f;
            #pragma unroll
            for (int bi = 0; bi < 4; ++bi) {
                float y = acc[ai][bi][r] * s[bi] + cc[bi];
                y = (y >= 0.f) ? y : SLOPE * y;
                a += y * w2v[bi];
            }
            p[ai][r] = a;
        }
    #pragma unroll
    for (int mask = 1; mask <= 8; mask <<= 1)
        #pragma unroll
        for (int ai = 0; ai < 4; ++ai)
            #pragma unroll
            for (int r = 0; r < 4; ++r)
                p[ai][r] += __shfl_xor(p[ai][r], mask);
    if (row16 == 0) {
        #pragma unroll
        for (int ai = 0; ai < 4; ++ai)
            #pragma unroll
            for (int r = 0; r < 4; ++r)
                red[wn][wm * 64 + ai * 16 + quad * 4 + r] = p[ai][r];
    }
    __syncthreads();
    if (tid < 128)
        out[(size_t)(m0 + tid) * THEADS + t] = red[0][tid] + red[1][tid] + b2[t];
}

extern "C" void kernel_launch(void* const* d_in, const int* in_sizes, int n_in,
                              void* d_out, int out_size, void* d_ws, size_t ws_size,
                              hipStream_t stream) {
    (void)in_sizes; (void)n_in; (void)out_size;
    const float* f     = (const float*)d_in[0];
    const float* W1    = (const float*)d_in[1];
    const float* b1    = (const float*)d_in[2];
    const float* gmm   = (const float*)d_in[3];
    const float* bta   = (const float*)d_in[4];
    const float* rmean = (const float*)d_in[5];
    const float* rvar  = (const float*)d_in[6];
    const float* W2    = (const float*)d_in[7];
    const float* b2    = (const float*)d_in[8];
    float* out = (float*)d_out;

    if (ws_size >= WS_NEED) {
        __hip_bfloat16* fb  = (__hip_bfloat16*)d_ws;
        __hip_bfloat16* W1b = fb + N_F;
        cvt_pass<<<(C_T8 + 255) / 256, 256, 0, stream>>>(f, W1, fb);
        dim3 grid(THEADS, BATCH / 256);
        fused_heads_bf16<<<grid, 512, 0, stream>>>(fb, W1b, b1, gmm, bta, rmean, rvar, W2, b2, out);
    } else {
        dim3 grid(BATCH / 128, THEADS);
        fused_heads_f32<<<grid, 256, 0, stream>>>(f, W1, b1, gmm, bta, rmean, rvar, W2, b2, out);
    }
}

// Round 9
// 223.936 us; speedup vs baseline: 1.6464x; 1.6464x over previous
//
#include <hip/hip_runtime.h>
#include <hip/hip_bf16.h>

// Problem constants
constexpr int BATCH = 8192;   // M
constexpr int THEADS = 137;   // number of predict heads
constexpr int DFEA = 384;     // reduction dim of GEMM1
constexpr int KHID = 128;     // per-head hidden width
constexpr float EPS_BN = 1e-5f;
constexpr float SLOPE = 0.01f;

constexpr size_t N_F  = (size_t)BATCH * DFEA;          // 3,145,728
constexpr size_t N_W1 = (size_t)THEADS * KHID * DFEA;  // 6,733,824
constexpr size_t WS_NEED = (N_F + N_W1) * sizeof(__hip_bfloat16);
constexpr int C_F8 = (int)(N_F / 8);                   // 393,216
constexpr int C_T8 = (int)((N_F + N_W1) / 8);          // 1,234,944

typedef __attribute__((ext_vector_type(8))) short bf16x8;   // 8 bf16 = 4 VGPRs
typedef __attribute__((ext_vector_type(4))) float f32x4;

__device__ __forceinline__ short cvt_bf16(float x) {
    __hip_bfloat16 b = __float2bfloat16(x);
    return *(short*)&b;
}

__device__ __forceinline__ bf16x8 load8_cvt(const float* __restrict__ g) {
    f32x4 lo = *(const f32x4*)g;
    f32x4 hi = *(const f32x4*)(g + 4);
    bf16x8 r;
    r[0] = cvt_bf16(lo[0]); r[1] = cvt_bf16(lo[1]);
    r[2] = cvt_bf16(lo[2]); r[3] = cvt_bf16(lo[3]);
    r[4] = cvt_bf16(hi[0]); r[5] = cvt_bf16(hi[1]);
    r[6] = cvt_bf16(hi[2]); r[7] = cvt_bf16(hi[3]);
    return r;
}

__device__ __forceinline__ void gload16(const void* g, void* s) {
    // async global->LDS, 16B/lane; HW dest = readfirstlane(base) + lane*16
    __builtin_amdgcn_global_load_lds((const __attribute__((address_space(1))) void*)g,
                                     (__attribute__((address_space(3))) void*)s,
                                     16, 0, 0);
}

// ---------------- pre-pass: fp32 -> bf16 bulk convert (f then W1, one launch) ----
__global__ __launch_bounds__(256) void cvt_pass(const float* __restrict__ f,
                                                const float* __restrict__ W1,
                                                __hip_bfloat16* __restrict__ ws) {
    int i = blockIdx.x * 256 + threadIdx.x;
    if (i < C_F8)
        *(bf16x8*)(ws + (size_t)i * 8) = load8_cvt(f + (size_t)i * 8);
    else if (i < C_T8)
        *(bf16x8*)(ws + (size_t)i * 8) = load8_cvt(W1 + ((size_t)i - C_F8) * 8);
}

// ---- main kernel: B-resident LDS + per-wave private A staging, barrier-free K-loop
// Block = (512 rows of f, head t). 8 waves, each 64 rows x 128 cols (full head).
// Bs: head's whole W1 slice 128x384 bf16 = 96 KB, staged once (one barrier).
// Aw: per-wave 64x32 buffer (4 KB), refilled each kt via global_load_lds.
// K-loop has NO __syncthreads: A ordering is per-wave (vmcnt is per-wave!), so
// one wave's drain overlaps other waves' MFMA. Explicit waits:
//   0x0F70 = s_waitcnt vmcnt(0)  (A(kt) landed in LDS)
//   0xC07F = s_waitcnt lgkmcnt(0) (frags in regs -> safe to overwrite buffer)
// Swizzles (conflict-free 2-way reads): A chunk c of row r at c^((r>>1)&3);
// B chunk c of row r at (c&~7)|((c^r)&7). Both applied at the staging SOURCE.
__global__ __launch_bounds__(512, 2) void fused_heads_bf16(
    const __hip_bfloat16* __restrict__ fb,     // [8192, 384] bf16
    const __hip_bfloat16* __restrict__ W1b,    // [137*128, 384] bf16
    const float* __restrict__ b1,
    const float* __restrict__ gmm,
    const float* __restrict__ bta,
    const float* __restrict__ rmean,
    const float* __restrict__ rvar,
    const float* __restrict__ W2,
    const float* __restrict__ b2,
    float* __restrict__ out)                   // [8192, 137]
{
    __shared__ __attribute__((aligned(16))) __hip_bfloat16 smem[65536]; // 128 KB
    __hip_bfloat16* Bs = smem;            // 49152 elems = 96 KB
    __hip_bfloat16* Aw = smem + 49152;    // 16384 elems = 32 KB (8 waves x 2048)

    const int tid  = threadIdx.x;
    const int lane = tid & 63;
    const int wave = tid >> 6;            // wave owns rows m0+wave*64 .. +64
    const int m0 = blockIdx.x * 512;      // m-tile fastest (L2 locality)
    const int t  = blockIdx.y;
    const int n0 = t * KHID;

    const int row16 = lane & 15;
    const int quad  = lane >> 4;

    // ---- stage whole B once: 6144 chunks of 16B; 12/thread; XOR swizzle ----
    #pragma unroll
    for (int j = 0; j < 12; ++j) {
        const int li = tid + j * 512;
        const int r  = li / 48, cp = li % 48;
        const int c  = (cp & ~7) | ((cp ^ r) & 7);
        gload16(W1b + (size_t)(n0 + r) * DFEA + c * 8, &Bs[(size_t)li * 8]);
    }

    // ---- per-wave A staging pointers (single 64x32 buffer) ----
    // chunk li = j*64+lane: row r = 16j + (lane>>2), dest chunk cp = lane&3,
    // source chunk c = cp ^ ((r>>1)&3) = (lane&3) ^ ((lane>>3)&3)
    const __hip_bfloat16* aSrc[4];
    #pragma unroll
    for (int j = 0; j < 4; ++j) {
        const int r = j * 16 + (lane >> 2);
        const int c = (lane & 3) ^ ((lane >> 3) & 3);
        aSrc[j] = fb + (size_t)(m0 + wave * 64 + r) * DFEA + c * 8;
    }
    __hip_bfloat16* aDst = Aw + wave * 2048;

    // stage A(kt=0)
    #pragma unroll
    for (int j = 0; j < 4; ++j)
        gload16(aSrc[j], aDst + j * 512 + lane * 8);

    __syncthreads();   // B + A(0) resident (single barrier in the kernel)

    // per-lane LDS read bases
    // A-frag: row r = ai*16+row16 -> elem wave*2048 + r*32 + (quad^((row16>>1)&3))*8
    const int aoff = wave * 2048 + row16 * 32 + (quad ^ ((row16 >> 1) & 3)) * 8;
    // B-frag: row nl = bi*16+row16; chunk gc = 4kt+quad;
    // LDS chunk = (gc&~7) + (u0 ^ 4*(kt&1)) with u0 = quad ^ (row16&7)
    const int u0 = quad ^ (row16 & 7);
    int bbase[8];
    #pragma unroll
    for (int bi = 0; bi < 8; ++bi)
        bbase[bi] = (bi * 16 + row16) * DFEA;

    f32x4 acc[4][8];
    #pragma unroll
    for (int i = 0; i < 4; ++i)
        #pragma unroll
        for (int j = 0; j < 8; ++j)
            acc[i][j] = (f32x4){0.f, 0.f, 0.f, 0.f};

    #pragma unroll
    for (int kt = 0; kt < DFEA / 32; ++kt) {
        __builtin_amdgcn_s_waitcnt(0x0F70);   // vmcnt(0): this wave's A(kt) landed

        bf16x8 af[4], bfr[8];
        #pragma unroll
        for (int ai = 0; ai < 4; ++ai)
            af[ai] = *(const bf16x8*)&Aw[aoff - wave * 2048 + wave * 2048 + ai * 512];
        const int gcb = (4 * kt) & ~7;
        const int v   = u0 ^ ((kt & 1) << 2);
        #pragma unroll
        for (int bi = 0; bi < 8; ++bi)
            bfr[bi] = *(const bf16x8*)&Bs[bbase[bi] + (gcb + v) * 8];

        __builtin_amdgcn_s_waitcnt(0xC07F);   // lgkmcnt(0): frags in regs

        if (kt + 1 < DFEA / 32) {             // overwrite own buffer (safe now)
            const int k1 = (kt + 1) * 32;
            #pragma unroll
            for (int j = 0; j < 4; ++j)
                gload16(aSrc[j] + k1, aDst + j * 512 + lane * 8);
        }

        #pragma unroll
        for (int ai = 0; ai < 4; ++ai)
            #pragma unroll
            for (int bi = 0; bi < 8; ++bi)
                acc[ai][bi] = __builtin_amdgcn_mfma_f32_16x16x32_bf16(
                    af[ai], bfr[bi], acc[ai][bi], 0, 0, 0);
    }

    // ---- fused epilogue: BN (eval) + LeakyReLU + dot with W2, all in-wave ----
    float s[8], cc[8], w2v[8];
    #pragma unroll
    for (int bi = 0; bi < 8; ++bi) {
        const int n = n0 + bi * 16 + row16;
        const float sv = gmm[n] * rsqrtf(rvar[n] + EPS_BN);
        s[bi]   = sv;
        cc[bi]  = bta[n] + (b1[n] - rmean[n]) * sv;
        w2v[bi] = W2[n];
    }

    float p[4][4];
    #pragma unroll
    for (int ai = 0; ai < 4; ++ai)
        #pragma unroll
        for (int r = 0; r < 4; ++r) {
            float a = 0.f;
            #pragma unroll
            for (int bi = 0; bi < 8; ++bi) {
                float y = acc[ai][bi][r] * s[bi] + cc[bi];
                y = (y >= 0.f) ? y : SLOPE * y;   // LeakyReLU
                a += y * w2v[bi];
            }
            p[ai][r] = a;
        }

    // reduce across the 16 column-lanes (C/D: col = lane&15)
    #pragma unroll
    for (int mask = 1; mask <= 8; mask <<= 1)
        #pragma unroll
        for (int ai = 0; ai < 4; ++ai)
            #pragma unroll
            for (int r = 0; r < 4; ++r)
                p[ai][r] += __shfl_xor(p[ai][r], mask);

    if (row16 == 0) {
        const float bias = b2[t];
        #pragma unroll
        for (int ai = 0; ai < 4; ++ai)
            #pragma unroll
            for (int r = 0; r < 4; ++r) {
                const int row = m0 + wave * 64 + ai * 16 + quad * 4 + r;
                out[(size_t)row * THEADS + t] = p[ai][r] + bias;
            }
    }
}

// ---------------- fallback: direct fp32 path (round-3 kernel, 128-tile) ------------
__global__ __launch_bounds__(256) void fused_heads_f32(
    const float* __restrict__ f, const float* __restrict__ W1,
    const float* __restrict__ b1, const float* __restrict__ gmm,
    const float* __restrict__ bta, const float* __restrict__ rmean,
    const float* __restrict__ rvar, const float* __restrict__ W2,
    const float* __restrict__ b2, float* __restrict__ out)
{
    __shared__ __attribute__((aligned(16))) __hip_bfloat16 As[128 * 32];
    __shared__ __attribute__((aligned(16))) __hip_bfloat16 Bs[128 * 32];
    __shared__ float red[2][128];

    const int tid  = threadIdx.x;
    const int lane = tid & 63;
    const int wave = tid >> 6;
    const int wm = wave >> 1, wn = wave & 1;
    const int m0 = blockIdx.x * 128;
    const int t  = blockIdx.y;
    const int n0 = t * KHID;

    const int li0 = tid, li1 = tid + 256;
    const int r0 = li0 >> 2, c0 = (li0 & 3) * 8;
    const int r1 = li1 >> 2, c1 = (li1 & 3) * 8;
    const float* gA0 = f  + (size_t)(m0 + r0) * DFEA + c0;
    const float* gA1 = f  + (size_t)(m0 + r1) * DFEA + c1;
    const float* gB0 = W1 + (size_t)(n0 + r0) * DFEA + c0;
    const float* gB1 = W1 + (size_t)(n0 + r1) * DFEA + c1;

    const int row16 = lane & 15, quad = lane >> 4;

    f32x4 acc[4][4];
    #pragma unroll
    for (int i = 0; i < 4; ++i)
        #pragma unroll
        for (int j = 0; j < 4; ++j)
            acc[i][j] = (f32x4){0.f, 0.f, 0.f, 0.f};

    #pragma unroll 1
    for (int kt = 0; kt < DFEA / 32; ++kt) {
        const int k0 = kt * 32;
        bf16x8 va0 = load8_cvt(gA0 + k0);
        bf16x8 va1 = load8_cvt(gA1 + k0);
        bf16x8 vb0 = load8_cvt(gB0 + k0);
        bf16x8 vb1 = load8_cvt(gB1 + k0);
        __syncthreads();
        *(bf16x8*)&As[li0 * 8] = va0;
        *(bf16x8*)&As[li1 * 8] = va1;
        *(bf16x8*)&Bs[li0 * 8] = vb0;
        *(bf16x8*)&Bs[li1 * 8] = vb1;
        __syncthreads();

        bf16x8 af[4], bfr[4];
        #pragma unroll
        for (int i = 0; i < 4; ++i)
            af[i] = *(const bf16x8*)&As[(wm * 64 + i * 16 + row16) * 32 + quad * 8];
        #pragma unroll
        for (int i = 0; i < 4; ++i)
            bfr[i] = *(const bf16x8*)&Bs[(wn * 64 + i * 16 + row16) * 32 + quad * 8];
        #pragma unroll
        for (int ai = 0; ai < 4; ++ai)
            #pragma unroll
            for (int bi = 0; bi < 4; ++bi)
                acc[ai][bi] = __builtin_amdgcn_mfma_f32_16x16x32_bf16(
                    af[ai], bfr[bi], acc[ai][bi], 0, 0, 0);
    }

    float s[4], cc[4], w2v[4];
    #pragma unroll
    for (int bi = 0; bi < 4; ++bi) {
        const int n = n0 + wn * 64 + bi * 16 + row16;
        const float sv = gmm[n] * rsqrtf(rvar[n] + EPS_BN);
        s[bi] = sv;
        cc[bi] = bta[n] + (b1[n] - rmean[n]) * sv;
        w2v[bi] = W2[n];
    }
    float p[4][4];
    #pragma unroll
    for (int ai = 0; ai < 4; ++ai)
        #pragma unroll
        for (int r = 0; r < 4; ++r) {
            float a = 0.f;
            #pragma unroll
            for (int bi = 0; bi < 4; ++bi) {
                float y = acc[ai][bi][r] * s[bi] + cc[bi];
                y = (y >= 0.f) ? y : SLOPE * y;
                a += y * w2v[bi];
            }
            p[ai][r] = a;
        }
    #pragma unroll
    for (int mask = 1; mask <= 8; mask <<= 1)
        #pragma unroll
        for (int ai = 0; ai < 4; ++ai)
            #pragma unroll
            for (int r = 0; r < 4; ++r)
                p[ai][r] += __shfl_xor(p[ai][r], mask);
    if (row16 == 0) {
        #pragma unroll
        for (int ai = 0; ai < 4; ++ai)
            #pragma unroll
            for (int r = 0; r < 4; ++r)
                red[wn][wm * 64 + ai * 16 + quad * 4 + r] = p[ai][r];
    }
    __syncthreads();
    if (tid < 128)
        out[(size_t)(m0 + tid) * THEADS + t] = red[0][tid] + red[1][tid] + b2[t];
}

extern "C" void kernel_launch(void* const* d_in, const int* in_sizes, int n_in,
                              void* d_out, int out_size, void* d_ws, size_t ws_size,
                              hipStream_t stream) {
    (void)in_sizes; (void)n_in; (void)out_size;
    const float* f     = (const float*)d_in[0];
    const float* W1    = (const float*)d_in[1];
    const float* b1    = (const float*)d_in[2];
    const float* gmm   = (const float*)d_in[3];
    const float* bta   = (const float*)d_in[4];
    const float* rmean = (const float*)d_in[5];
    const float* rvar  = (const float*)d_in[6];
    const float* W2    = (const float*)d_in[7];
    const float* b2    = (const float*)d_in[8];
    float* out = (float*)d_out;

    if (ws_size >= WS_NEED) {
        __hip_bfloat16* fb  = (__hip_bfloat16*)d_ws;
        __hip_bfloat16* W1b = fb + N_F;
        cvt_pass<<<(C_T8 + 255) / 256, 256, 0, stream>>>(f, W1, fb);
        dim3 grid(BATCH / 512, THEADS);   // m-tile fastest: good L2 locality
        fused_heads_bf16<<<grid, 512, 0, stream>>>(fb, W1b, b1, gmm, bta, rmean, rvar, W2, b2, out);
    } else {
        dim3 grid(BATCH / 128, THEADS);
        fused_heads_f32<<<grid, 256, 0, stream>>>(f, W1, b1, gmm, bta, rmean, rvar, W2, b2, out);
    }
}